// Round 9
// baseline (448.604 us; speedup 1.0000x reference)
//
#include <hip/hip_runtime.h>

// DeepseekV3MoEToA2AAdapter: T=2048 tokens, H=1024, E=8, I=1408, top-2.
// fp32 I/O. No weight-transpose pass: GEMM blocks hold their whole B panel
// (BN=32 columns x full K) resident in LDS, filled fp32->bf16 during the
// FIRST m-tile's K-loop; subsequent m-tiles reuse it. 1 block/CU by LDS.
#define T_TOK 2048
#define HDIM  1024
#define NEXP  8
#define IDIM  1408

#define BMT  256    // m rows per tile (4 waves x 64)
#define BK   32
#define KPAD 40     // As row stride (u16)
#define GU_KP 1032  // gate/up panel row stride (u16), K=1024 (+8 pad)
#define DN_KP 1416  // down panel row stride (u16), K=1408 (+8 pad)

typedef __attribute__((ext_vector_type(8))) short bf16x8;
typedef __attribute__((ext_vector_type(4))) float f32x4;

static __device__ __forceinline__ unsigned short f2bf(float f) {
    union { float f; unsigned u; } a; a.f = f;
    return (unsigned short)((a.u + 0x7fffu + ((a.u >> 16) & 1u)) >> 16);
}

// ------------------------------------------------- router (+ x -> bf16) ----
// rw staged transposed in LDS (stride-1 reads); fp64 accumulation for robust
// top-2 ordering; softmax+top2+renorm == sigmoid of logit difference.
__global__ __launch_bounds__(256) void router_kernel(
    const float* __restrict__ x,        // [T, H]
    const float* __restrict__ rw,       // [H, E]
    int*   __restrict__ counts,
    int*   __restrict__ tok_list,       // [E][T]
    float* __restrict__ wgt_list,       // [E][T]
    int*   __restrict__ row_list,       // [E][T]
    unsigned short* __restrict__ xb)    // [T, H] bf16
{
    __shared__ float rwT[NEXP][HDIM];   // 32 KB
    const int tid = threadIdx.x;
#pragma unroll
    for (int p = 0; p < 4; ++p) {
        const int h = tid + 256 * p;
        const float4 a = *(const float4*)(rw + (size_t)h * 8);
        const float4 b = *(const float4*)(rw + (size_t)h * 8 + 4);
        rwT[0][h] = a.x; rwT[1][h] = a.y; rwT[2][h] = a.z; rwT[3][h] = a.w;
        rwT[4][h] = b.x; rwT[5][h] = b.y; rwT[6][h] = b.z; rwT[7][h] = b.w;
    }
    __syncthreads();

    const int wave = (blockIdx.x * blockDim.x + threadIdx.x) >> 6;
    const int lane = threadIdx.x & 63;
    if (wave >= T_TOK) return;
    const int t = wave;

    float xr[16];
    const float* xp = x + (size_t)t * HDIM;
#pragma unroll
    for (int i = 0; i < 16; ++i) xr[i] = xp[lane + 64 * i];

    unsigned short* xbp = xb + (size_t)t * HDIM;
#pragma unroll
    for (int i = 0; i < 16; ++i) xbp[lane + 64 * i] = f2bf(xr[i]);

    double logits[NEXP];
#pragma unroll
    for (int e = 0; e < NEXP; ++e) {
        double s = 0.0;
#pragma unroll
        for (int i = 0; i < 16; ++i)
            s += (double)xr[i] * (double)rwT[e][lane + 64 * i];
#pragma unroll
        for (int off = 32; off > 0; off >>= 1)
            s += __shfl_down(s, off, 64);
        logits[e] = s;
    }

    if (lane == 0) {
        int e1 = 0;
        for (int e = 1; e < NEXP; ++e) if (logits[e] > logits[e1]) e1 = e;
        int e2 = -1;
        for (int e = 0; e < NEXP; ++e) {
            if (e == e1) continue;
            if (e2 < 0 || logits[e] > logits[e2]) e2 = e;
        }
        const double w1 = 1.0 / (1.0 + exp(logits[e2] - logits[e1]));
        const double w2 = 1.0 - w1;
        int p1 = atomicAdd(&counts[e1], 1);
        tok_list[e1 * T_TOK + p1] = t;
        wgt_list[e1 * T_TOK + p1] = (float)w1;
        row_list[e1 * T_TOK + p1] = 2 * t;
        int p2 = atomicAdd(&counts[e2], 1);
        tok_list[e2 * T_TOK + p2] = t;
        wgt_list[e2 * T_TOK + p2] = (float)w2;
        row_list[e2 * T_TOK + p2] = 2 * t + 1;
    }
}

// ---------------------------------------------- gate+up, panel-resident ----
// Block = (e, nt of 44). LDS holds Bg,Bu [32][1024] bf16 panels. m-tile 0
// fills the panels from fp32 global during its K-loop; m-tiles 1.. reuse.
__global__ __launch_bounds__(256) void gateup_kernel(
    const unsigned short* __restrict__ xb,    // [T,H] bf16
    const float* __restrict__ gw,             // [E][H][I] fp32
    const float* __restrict__ uw,
    const float* __restrict__ gb, const float* __restrict__ ub,
    const int* __restrict__ counts,
    const int* __restrict__ tok_list,
    const int* __restrict__ row_list,
    unsigned short* __restrict__ act)         // [2T, IDIM] bf16
{
    const int e  = blockIdx.x / 44;
    const int nt = blockIdx.x % 44;
    const int n_e = counts[e];
    if (n_e <= 0) return;
    const int n0 = nt * 32;

    const float* gwp = gw + (size_t)e * HDIM * IDIM;   // [K=1024][N=1408]
    const float* uwp = uw + (size_t)e * HDIM * IDIM;
    const float* gbp = gb + (size_t)e * IDIM;
    const float* ubp = ub + (size_t)e * IDIM;

    __shared__ unsigned short Bg[32][GU_KP];   // 66048 B
    __shared__ unsigned short Bu[32][GU_KP];   // 66048 B
    __shared__ unsigned short As[BMT][KPAD];   // 20480 B
    __shared__ int gr_lds[BMT];
    __shared__ int or_lds[BMT];

    const int tid = threadIdx.x;
    // panel fill mapping: 128 threads per panel; 32 k-rows x 4 col-groups of 8
    const int bu  = tid & 127;
    const int bkk = bu >> 2;           // k row within 32-step
    const int bc0 = (bu & 3) * 8;      // col start (8 cols = 2 float4)
    const float* bsrc0 = ((tid >> 7) ? uwp : gwp) + (size_t)bkk * IDIM + n0 + bc0;
    unsigned short* Bpan = ((tid >> 7) ? &Bu[0][0] : &Bg[0][0]);

    const int wv = tid >> 6, lane = tid & 63;
    const int wm = wv * 64;
    const int l16 = lane & 15, quad = lane >> 4;
    const int base = e * T_TOK;
    const int nmt = (n_e + BMT - 1) / BMT;

    for (int mt = 0; mt < nmt; ++mt) {
        const int m0 = mt * BMT;
        __syncthreads();   // prev m-tile epilogue done (or first pass: no-op)
        {
            const int m = m0 + tid;
            int g = -1, o = -1;
            if (m < n_e) { g = tok_list[base + m]; o = row_list[base + m]; }
            gr_lds[tid] = g; or_lds[tid] = o;
        }
        __syncthreads();

        const int arow = gr_lds[tid];
        const unsigned short* ap = xb + (size_t)(arow < 0 ? 0 : arow) * HDIM;

        f32x4 accg[4][2], accu[4][2];
        const f32x4 zero = {0.f, 0.f, 0.f, 0.f};
#pragma unroll
        for (int i = 0; i < 4; ++i)
#pragma unroll
            for (int j = 0; j < 2; ++j) { accg[i][j] = zero; accu[i][j] = zero; }

        uint4 PA0 = {0,0,0,0}, PA1 = {0,0,0,0}, PA2 = {0,0,0,0}, PA3 = {0,0,0,0};
        if (arow >= 0) {
            PA0 = *(const uint4*)(ap);
            PA1 = *(const uint4*)(ap + 8);
            PA2 = *(const uint4*)(ap + 16);
            PA3 = *(const uint4*)(ap + 24);
        }
        float4 PB0, PB1;
        if (mt == 0) {
            PB0 = *(const float4*)(bsrc0);
            PB1 = *(const float4*)(bsrc0 + 4);
        }

        for (int k0 = 0; k0 < HDIM; k0 += BK) {
            __syncthreads();
            *(uint4*)&As[tid][0]  = PA0;
            *(uint4*)&As[tid][8]  = PA1;
            *(uint4*)&As[tid][16] = PA2;
            *(uint4*)&As[tid][24] = PA3;
            if (mt == 0) {
                const float* f0 = (const float*)&PB0;
                const float* f1 = (const float*)&PB1;
#pragma unroll
                for (int i = 0; i < 4; ++i) {
                    Bpan[(size_t)(bc0 + i) * GU_KP + k0 + bkk]     = f2bf(f0[i]);
                    Bpan[(size_t)(bc0 + 4 + i) * GU_KP + k0 + bkk] = f2bf(f1[i]);
                }
            }
            __syncthreads();

            const int kn = k0 + BK;
            if (kn < HDIM) {
                if (arow >= 0) {
                    PA0 = *(const uint4*)(ap + kn);
                    PA1 = *(const uint4*)(ap + kn + 8);
                    PA2 = *(const uint4*)(ap + kn + 16);
                    PA3 = *(const uint4*)(ap + kn + 24);
                }
                if (mt == 0) {
                    const float* bp = bsrc0 + (size_t)kn * IDIM;
                    PB0 = *(const float4*)(bp);
                    PB1 = *(const float4*)(bp + 4);
                }
            }

            bf16x8 af[4], bgf[2], buf[2];
#pragma unroll
            for (int i = 0; i < 4; ++i)
                af[i] = *(const bf16x8*)&As[wm + i * 16 + l16][quad * 8];
#pragma unroll
            for (int j = 0; j < 2; ++j) {
                bgf[j] = *(const bf16x8*)&Bg[j * 16 + l16][k0 + quad * 8];
                buf[j] = *(const bf16x8*)&Bu[j * 16 + l16][k0 + quad * 8];
            }
#pragma unroll
            for (int i = 0; i < 4; ++i)
#pragma unroll
                for (int j = 0; j < 2; ++j) {
                    accg[i][j] = __builtin_amdgcn_mfma_f32_16x16x32_bf16(
                        af[i], bgf[j], accg[i][j], 0, 0, 0);
                    accu[i][j] = __builtin_amdgcn_mfma_f32_16x16x32_bf16(
                        af[i], buf[j], accu[i][j], 0, 0, 0);
                }
        }

        // epilogue: silu(g)*u -> bf16 act
#pragma unroll
        for (int j = 0; j < 2; ++j) {
            const int nl = n0 + j * 16 + l16;
            const float gbv = gbp[nl];
            const float ubv = ubp[nl];
#pragma unroll
            for (int i = 0; i < 4; ++i) {
#pragma unroll
                for (int ii = 0; ii < 4; ++ii) {
                    const int ml = wm + i * 16 + quad * 4 + ii;
                    const int orow = or_lds[ml];
                    if (orow >= 0) {
                        const float g = accg[i][j][ii] + gbv;
                        const float uu = accu[i][j][ii] + ubv;
                        act[(size_t)orow * IDIM + nl] =
                            f2bf(g * uu / (1.0f + __expf(-g)));
                    }
                }
            }
        }
    }
}

// ---------------------------------------------- down-proj, panel-resident ---
// Block = (e, nt of 32). LDS holds Bs [32][1408] bf16; full-K (no split),
// plain stores to y2 (pair rows), combine sums the 2 pair rows.
__global__ __launch_bounds__(256) void down_kernel(
    const unsigned short* __restrict__ act,   // [2T, IDIM] bf16
    const float* __restrict__ dw,             // [E][I][H] fp32
    const float* __restrict__ db,
    const int* __restrict__ counts,
    const float* __restrict__ wgt_list,
    const int* __restrict__ row_list,
    float* __restrict__ y2)                   // [2T, HDIM] fp32
{
    const int e  = blockIdx.x >> 5;
    const int nt = blockIdx.x & 31;
    const int n_e = counts[e];
    if (n_e <= 0) return;
    const int n0 = nt * 32;

    const float* dwp = dw + (size_t)e * IDIM * HDIM;   // [K=1408][N=1024]
    const float* dbp = db + (size_t)e * HDIM;

    __shared__ unsigned short Bs[32][DN_KP];   // 90624 B
    __shared__ unsigned short As[BMT][KPAD];   // 20480 B
    __shared__ int   r_lds[BMT];
    __shared__ float w_lds[BMT];

    const int tid = threadIdx.x;
    // panel fill: 256 threads; 32 k-rows x 8 col-groups of 4
    const int bkk = tid >> 3;          // k row within 32-step
    const int bc0 = (tid & 7) * 4;     // col start (1 float4)
    const float* bsrc0 = dwp + (size_t)bkk * HDIM + n0 + bc0;

    const int wv = tid >> 6, lane = tid & 63;
    const int wm = wv * 64;
    const int l16 = lane & 15, quad = lane >> 4;
    const int base = e * T_TOK;
    const int nmt = (n_e + BMT - 1) / BMT;

    for (int mt = 0; mt < nmt; ++mt) {
        const int m0 = mt * BMT;
        __syncthreads();
        {
            const int m = m0 + tid;
            int r = -1; float w = 0.0f;
            if (m < n_e) { r = row_list[base + m]; w = wgt_list[base + m]; }
            r_lds[tid] = r; w_lds[tid] = w;
        }
        __syncthreads();

        const int arow = r_lds[tid];
        const unsigned short* ap = act + (size_t)(arow < 0 ? 0 : arow) * IDIM;

        f32x4 acc[4][2];
        const f32x4 zero = {0.f, 0.f, 0.f, 0.f};
#pragma unroll
        for (int i = 0; i < 4; ++i)
#pragma unroll
            for (int j = 0; j < 2; ++j) acc[i][j] = zero;

        uint4 PA0 = {0,0,0,0}, PA1 = {0,0,0,0}, PA2 = {0,0,0,0}, PA3 = {0,0,0,0};
        if (arow >= 0) {
            PA0 = *(const uint4*)(ap);
            PA1 = *(const uint4*)(ap + 8);
            PA2 = *(const uint4*)(ap + 16);
            PA3 = *(const uint4*)(ap + 24);
        }
        float4 PB;
        if (mt == 0) PB = *(const float4*)(bsrc0);

        for (int k0 = 0; k0 < IDIM; k0 += BK) {
            __syncthreads();
            *(uint4*)&As[tid][0]  = PA0;
            *(uint4*)&As[tid][8]  = PA1;
            *(uint4*)&As[tid][16] = PA2;
            *(uint4*)&As[tid][24] = PA3;
            if (mt == 0) {
                const float* f0 = (const float*)&PB;
#pragma unroll
                for (int i = 0; i < 4; ++i)
                    Bs[0][(size_t)(bc0 + i) * DN_KP + k0 + bkk] = f2bf(f0[i]);
            }
            __syncthreads();

            const int kn = k0 + BK;
            if (kn < IDIM) {
                if (arow >= 0) {
                    PA0 = *(const uint4*)(ap + kn);
                    PA1 = *(const uint4*)(ap + kn + 8);
                    PA2 = *(const uint4*)(ap + kn + 16);
                    PA3 = *(const uint4*)(ap + kn + 24);
                }
                if (mt == 0) PB = *(const float4*)(bsrc0 + (size_t)kn * HDIM);
            }

            bf16x8 af[4], bfr[2];
#pragma unroll
            for (int i = 0; i < 4; ++i)
                af[i] = *(const bf16x8*)&As[wm + i * 16 + l16][quad * 8];
#pragma unroll
            for (int j = 0; j < 2; ++j)
                bfr[j] = *(const bf16x8*)&Bs[j * 16 + l16][k0 + quad * 8];
#pragma unroll
            for (int i = 0; i < 4; ++i)
#pragma unroll
                for (int j = 0; j < 2; ++j)
                    acc[i][j] = __builtin_amdgcn_mfma_f32_16x16x32_bf16(
                        af[i], bfr[j], acc[i][j], 0, 0, 0);
        }

#pragma unroll
        for (int j = 0; j < 2; ++j) {
            const int nl = n0 + j * 16 + l16;
            const float bv = dbp[nl];
#pragma unroll
            for (int i = 0; i < 4; ++i) {
#pragma unroll
                for (int ii = 0; ii < 4; ++ii) {
                    const int ml = wm + i * 16 + quad * 4 + ii;
                    const int rr = r_lds[ml];
                    if (rr >= 0)
                        y2[(size_t)rr * HDIM + nl] =
                            w_lds[ml] * (acc[i][j][ii] + bv);
                }
            }
        }
    }
}

// --------------------------------------------------------------- combine ----
__global__ __launch_bounds__(256) void combine_kernel(
    const float* __restrict__ y2, float* __restrict__ out)
{
    const int idx = (blockIdx.x * 256 + threadIdx.x) * 4;   // < T*H
    const int t = idx >> 10;           // HDIM == 1024
    const int h = idx & 1023;
    const float4 a = *(const float4*)(y2 + ((size_t)2 * t) * HDIM + h);
    const float4 b = *(const float4*)(y2 + ((size_t)2 * t + 1) * HDIM + h);
    float4 o;
    o.x = a.x + b.x; o.y = a.y + b.y; o.z = a.z + b.z; o.w = a.w + b.w;
    *(float4*)(out + idx) = o;
}

// ---------------------------------------------------------------- launch ----
extern "C" void kernel_launch(void* const* d_in, const int* in_sizes, int n_in,
                              void* d_out, int out_size, void* d_ws, size_t ws_size,
                              hipStream_t stream)
{
    const float* x      = (const float*)d_in[0];
    const float* rw     = (const float*)d_in[1];
    const float* gate_w = (const float*)d_in[2];
    const float* up_w   = (const float*)d_in[3];
    const float* down_w = (const float*)d_in[4];
    const float* gate_b = (const float*)d_in[5];
    const float* up_b   = (const float*)d_in[6];
    const float* down_b = (const float*)d_in[7];
    float* out = (float*)d_out;

    // workspace (~32 MB)
    char* ws = (char*)d_ws;
    size_t off = 0;
    int*   counts   = (int*)(ws + off);  off += 256;
    int*   tok_list = (int*)(ws + off);  off += 65536;
    float* wgt_list = (float*)(ws + off); off += 65536;
    int*   row_list = (int*)(ws + off);  off += 65536;
    unsigned short* x_bf = (unsigned short*)(ws + off); off += (size_t)T_TOK * HDIM * 2;     // 4 MB
    unsigned short* act  = (unsigned short*)(ws + off); off += (size_t)2 * T_TOK * IDIM * 2; // 11.5 MB
    float* y2 = (float*)(ws + off);                                                          // 16 MB

    (void)hipMemsetAsync(counts, 0, 256, stream);

    router_kernel<<<T_TOK / 4, 256, 0, stream>>>(x, rw, counts, tok_list,
                                                 wgt_list, row_list, x_bf);

    gateup_kernel<<<NEXP * 44, 256, 0, stream>>>(
        x_bf, gate_w, up_w, gate_b, up_b, counts, tok_list, row_list, act);

    down_kernel<<<NEXP * 32, 256, 0, stream>>>(
        act, down_w, down_b, counts, wgt_list, row_list, y2);

    combine_kernel<<<(T_TOK * HDIM / 4) / 256, 256, 0, stream>>>(y2, out);
}

// Round 10
// 326.915 us; speedup vs baseline: 1.3722x; 1.3722x over previous
//
#include <hip/hip_runtime.h>

// DeepseekV3MoEToA2AAdapter: T=2048 tokens, H=1024, E=8, I=1408, top-2.
// fp32 I/O. Pipeline: register-transpose weight cast (no LDS) -> bf16 [E][N][K],
// LDS-staged router (+x->bf16), r8-style MFMA GEMMs, non-atomic split-K down.
#define T_TOK 2048
#define HDIM  1024
#define NEXP  8
#define IDIM  1408

#define BM 128
#define BN 64
#define BK 32
#define KPAD 40     // bf16 elems; 80 B rows, 16B-aligned
#define MT_SLOTS 16
#define GU_NT 22    // IDIM / BN
#define DN_NT 16    // HDIM / BN
#define DK_HALF 704 // IDIM / 2 (split-K for down)

typedef __attribute__((ext_vector_type(8))) short bf16x8;
typedef __attribute__((ext_vector_type(4))) float f32x4;

static __device__ __forceinline__ unsigned short f2bf(float f) {
    union { float f; unsigned u; } a; a.f = f;
    return (unsigned short)((a.u + 0x7fffu + ((a.u >> 16) & 1u)) >> 16);
}

// ------------------------------------------------- router (+ x -> bf16) ----
// rw staged transposed in LDS (stride-1 conflict-free); fp64 accumulation.
__global__ __launch_bounds__(256) void router_kernel(
    const float* __restrict__ x,        // [T, H]
    const float* __restrict__ rw,       // [H, E]
    int*   __restrict__ counts,
    int*   __restrict__ tok_list,       // [E][T]
    float* __restrict__ wgt_list,       // [E][T]
    int*   __restrict__ row_list,       // [E][T]
    unsigned short* __restrict__ xb)    // [T, H] bf16
{
    __shared__ float rwT[NEXP][HDIM];   // 32 KB
    const int tid = threadIdx.x;
#pragma unroll
    for (int p = 0; p < 4; ++p) {
        const int h = tid + 256 * p;
        const float4 a = *(const float4*)(rw + (size_t)h * 8);
        const float4 b = *(const float4*)(rw + (size_t)h * 8 + 4);
        rwT[0][h] = a.x; rwT[1][h] = a.y; rwT[2][h] = a.z; rwT[3][h] = a.w;
        rwT[4][h] = b.x; rwT[5][h] = b.y; rwT[6][h] = b.z; rwT[7][h] = b.w;
    }
    __syncthreads();

    const int wave = (blockIdx.x * blockDim.x + threadIdx.x) >> 6;
    const int lane = threadIdx.x & 63;
    if (wave >= T_TOK) return;
    const int t = wave;

    float xr[16];
    const float* xp = x + (size_t)t * HDIM;
#pragma unroll
    for (int i = 0; i < 16; ++i) xr[i] = xp[lane + 64 * i];

    unsigned short* xbp = xb + (size_t)t * HDIM;
#pragma unroll
    for (int i = 0; i < 16; ++i) xbp[lane + 64 * i] = f2bf(xr[i]);

    double logits[NEXP];
#pragma unroll
    for (int e = 0; e < NEXP; ++e) {
        double s = 0.0;
#pragma unroll
        for (int i = 0; i < 16; ++i)
            s += (double)xr[i] * (double)rwT[e][lane + 64 * i];
#pragma unroll
        for (int off = 32; off > 0; off >>= 1)
            s += __shfl_down(s, off, 64);
        logits[e] = s;
    }

    if (lane == 0) {
        int e1 = 0;
        for (int e = 1; e < NEXP; ++e) if (logits[e] > logits[e1]) e1 = e;
        int e2 = -1;
        for (int e = 0; e < NEXP; ++e) {
            if (e == e1) continue;
            if (e2 < 0 || logits[e] > logits[e2]) e2 = e;
        }
        const double w1 = 1.0 / (1.0 + exp(logits[e2] - logits[e1]));
        const double w2 = 1.0 - w1;
        int p1 = atomicAdd(&counts[e1], 1);
        tok_list[e1 * T_TOK + p1] = t;
        wgt_list[e1 * T_TOK + p1] = (float)w1;
        row_list[e1 * T_TOK + p1] = 2 * t;
        int p2 = atomicAdd(&counts[e2], 1);
        tok_list[e2 * T_TOK + p2] = t;
        wgt_list[e2 * T_TOK + p2] = (float)w2;
        row_list[e2 * T_TOK + p2] = 2 * t + 1;
    }
}

// ---------------------- weight cast+transpose, register-only (no LDS) -------
// fp32 [E][K][N] -> bf16 [E][N][K].  Block tile = 64k x 128n, 4 waves.
// Lane owns an 8k x 4n micro-tile: reads are 256B-contiguous per 16 lanes,
// writes are 64B-contiguous per 4 lanes. Zero LDS, zero bank conflicts.
// Unified grid: 176 blocks/tensor-expert: z<8 gate (K=1024,N=1408, 16x11),
// z<16 up, z>=16 down (K=1408,N=1024, 22x8).
__global__ __launch_bounds__(256) void wtrans_all_kernel(
    const float* __restrict__ gw, const float* __restrict__ uw,
    const float* __restrict__ dw,
    unsigned short* __restrict__ gwt, unsigned short* __restrict__ uwt,
    unsigned short* __restrict__ dwt)
{
    const int z  = blockIdx.z;
    const int bx = blockIdx.x;          // 0..175
    const float* src; unsigned short* dst; int K, N, kb, nb;
    if (z < 16) {
        K = HDIM; N = IDIM;
        const int e = z & 7;
        src = (z < 8 ? gw : uw) + (size_t)e * K * N;
        dst = (z < 8 ? gwt : uwt) + (size_t)e * (size_t)N * K;
        nb = bx % 11; kb = bx / 11;     // 11 n-tiles x 16 k-tiles
    } else {
        K = IDIM; N = HDIM;
        const int e = z - 16;
        src = dw + (size_t)e * K * N;
        dst = dwt + (size_t)e * (size_t)N * K;
        nb = bx & 7; kb = bx >> 3;      // 8 n-tiles x 22 k-tiles
    }

    const int tid  = threadIdx.x;
    const int wv   = tid >> 6;
    const int lane = tid & 63;
    const int k0 = kb * 64 + (wv >> 1) * 32 + (lane >> 4) * 8;   // 8 k rows
    const int n0 = nb * 128 + (wv & 1) * 64 + (lane & 15) * 4;   // 4 n cols

    float4 v[8];
#pragma unroll
    for (int r = 0; r < 8; ++r)
        v[r] = *(const float4*)(src + (size_t)(k0 + r) * N + n0);

#pragma unroll
    for (int i = 0; i < 4; ++i) {
        const float* f = (const float*)&v[0];
        ushort4 lo, hi;
        lo.x = f2bf(((const float*)&v[0])[i]);
        lo.y = f2bf(((const float*)&v[1])[i]);
        lo.z = f2bf(((const float*)&v[2])[i]);
        lo.w = f2bf(((const float*)&v[3])[i]);
        hi.x = f2bf(((const float*)&v[4])[i]);
        hi.y = f2bf(((const float*)&v[5])[i]);
        hi.z = f2bf(((const float*)&v[6])[i]);
        hi.w = f2bf(((const float*)&v[7])[i]);
        unsigned short* dp = dst + (size_t)(n0 + i) * K + k0;
        *(ushort4*)(dp)     = lo;
        *(ushort4*)(dp + 4) = hi;
        (void)f;
    }
}

// -------------------------------------------------- fused gate+up GEMM -----
__global__ __launch_bounds__(256) void gateup_kernel(
    const unsigned short* __restrict__ xb,    // [T,H] bf16
    const unsigned short* __restrict__ gwt,   // [E][I][H] bf16
    const unsigned short* __restrict__ uwt,   // [E][I][H] bf16
    const float* __restrict__ gb, const float* __restrict__ ub,
    const int* __restrict__ counts,
    const int* __restrict__ tok_list,
    const int* __restrict__ row_list,
    unsigned short* __restrict__ act)         // [2T, IDIM] bf16
{
    const int flat = blockIdx.x;
    const int xcd  = flat & 7;
    const int q    = flat >> 3;
    const int mt   = q & 15;
    const int slot = q >> 4;
    const int P    = slot * 8 + xcd;   // 0..175 = (e, nt), fixed XCD per (e,nt)
    const int e    = P / GU_NT;
    const int nt   = P % GU_NT;
    const int n_e  = counts[e];
    const int m0   = mt * BM;
    if (m0 >= n_e) return;
    const int n0 = nt * BN;

    const unsigned short* gwp = gwt + (size_t)e * IDIM * HDIM;
    const unsigned short* uwp = uwt + (size_t)e * IDIM * HDIM;
    const float* gbp = gb + (size_t)e * IDIM;
    const float* ubp = ub + (size_t)e * IDIM;

    __shared__ unsigned short As[BM][KPAD];
    __shared__ unsigned short Bg[BN][KPAD];
    __shared__ unsigned short Bu[BN][KPAD];
    __shared__ int gr_lds[BM];
    __shared__ int or_lds[BM];

    const int tid = threadIdx.x;
    const int base = e * T_TOK;
    if (tid < BM) {
        const int m = m0 + tid;
        int g = -1, o = -1;
        if (m < n_e) { g = tok_list[base + m]; o = row_list[base + m]; }
        gr_lds[tid] = g; or_lds[tid] = o;
    }
    __syncthreads();

    const int ar = tid >> 1;
    const int ac = (tid & 1) * 16;
    const int arow = gr_lds[ar];
    const unsigned short* ap = xb + (size_t)(arow < 0 ? 0 : arow) * HDIM;
    const int u   = tid & 127;
    const int brow = u >> 1;
    const int bch  = (u & 1) * 16;
    const unsigned short* bsrc =
        ((tid >> 7) ? uwp : gwp) + (size_t)(n0 + brow) * HDIM + bch;
    unsigned short* Bdst =
        ((tid >> 7) ? &Bu[0][0] : &Bg[0][0]) + brow * KPAD + bch;

    const int wv = tid >> 6, lane = tid & 63;
    const int wm = (wv & 1) * 64, wn = (wv >> 1) * 32;
    const int l16 = lane & 15, quad = lane >> 4;

    f32x4 accg[4][2], accu[4][2];
    const f32x4 zero = {0.0f, 0.0f, 0.0f, 0.0f};
#pragma unroll
    for (int i = 0; i < 4; ++i)
#pragma unroll
        for (int j = 0; j < 2; ++j) { accg[i][j] = zero; accu[i][j] = zero; }

    uint4 PA0 = {0,0,0,0}, PA1 = {0,0,0,0}, PB0, PB1;
    if (arow >= 0) {
        PA0 = *(const uint4*)(ap + ac);
        PA1 = *(const uint4*)(ap + ac + 8);
    }
    PB0 = *(const uint4*)(bsrc);
    PB1 = *(const uint4*)(bsrc + 8);

    for (int k0 = 0; k0 < HDIM; k0 += BK) {
        __syncthreads();
        *(uint4*)&As[ar][ac]       = PA0;
        *(uint4*)&As[ar][ac + 8]   = PA1;
        *(uint4*)(Bdst)            = PB0;
        *(uint4*)(Bdst + 8)        = PB1;
        __syncthreads();

        const int kn = k0 + BK;
        if (kn < HDIM) {
            if (arow >= 0) {
                PA0 = *(const uint4*)(ap + kn + ac);
                PA1 = *(const uint4*)(ap + kn + ac + 8);
            }
            PB0 = *(const uint4*)(bsrc + kn);
            PB1 = *(const uint4*)(bsrc + kn + 8);
        }

        bf16x8 af[4], bgf[2], buf[2];
#pragma unroll
        for (int i = 0; i < 4; ++i)
            af[i] = *(const bf16x8*)&As[wm + i * 16 + l16][quad * 8];
#pragma unroll
        for (int j = 0; j < 2; ++j) {
            bgf[j] = *(const bf16x8*)&Bg[wn + j * 16 + l16][quad * 8];
            buf[j] = *(const bf16x8*)&Bu[wn + j * 16 + l16][quad * 8];
        }
#pragma unroll
        for (int i = 0; i < 4; ++i)
#pragma unroll
            for (int j = 0; j < 2; ++j) {
                accg[i][j] = __builtin_amdgcn_mfma_f32_16x16x32_bf16(
                    af[i], bgf[j], accg[i][j], 0, 0, 0);
                accu[i][j] = __builtin_amdgcn_mfma_f32_16x16x32_bf16(
                    af[i], buf[j], accu[i][j], 0, 0, 0);
            }
    }

    // epilogue: silu(g)*u -> bf16 act
#pragma unroll
    for (int j = 0; j < 2; ++j) {
        const int nl = n0 + wn + j * 16 + l16;
        const float gbv = gbp[nl];
        const float ubv = ubp[nl];
#pragma unroll
        for (int i = 0; i < 4; ++i) {
#pragma unroll
            for (int ii = 0; ii < 4; ++ii) {
                const int ml = wm + i * 16 + quad * 4 + ii;
                const int orow = or_lds[ml];
                if (orow >= 0) {
                    const float g = accg[i][j][ii] + gbv;
                    const float uu = accu[i][j][ii] + ubv;
                    act[(size_t)orow * IDIM + nl] =
                        f2bf(g * uu / (1.0f + __expf(-g)));
                }
            }
        }
    }
}

// ------------------------------------------------------- down-proj GEMM ----
// Split-K=2, NON-ATOMIC: slice sk writes plain stores into y2 + sk*(2T*H).
__global__ __launch_bounds__(256) void down_kernel(
    const unsigned short* __restrict__ act,   // [2T, IDIM] bf16
    const unsigned short* __restrict__ dwt,   // [E][H][I] bf16
    const float* __restrict__ db,
    const int* __restrict__ counts,
    const float* __restrict__ wgt_list,
    const int* __restrict__ row_list,
    float* __restrict__ y2)                   // [2][2T, HDIM] fp32
{
    const int flat = blockIdx.x;
    const int xcd  = flat & 7;
    const int q    = flat >> 3;
    const int mt   = q & 15;
    const int slot = q >> 4;
    const int P    = slot * 8 + xcd;   // 0..255 = (sk, e, nt)
    const int sk   = P & 1;
    const int en   = P >> 1;
    const int e    = en >> 4;
    const int nt   = en & 15;
    const int n_e  = counts[e];
    const int m0   = mt * BM;
    if (m0 >= n_e) return;
    const int n0 = nt * BN;
    const int ks = sk * DK_HALF;
    float* y2s = y2 + (size_t)sk * 2 * T_TOK * HDIM;

    const unsigned short* dwp = dwt + (size_t)e * HDIM * IDIM;
    const float* dbp = db + (size_t)e * HDIM;

    __shared__ unsigned short As[BM][KPAD];
    __shared__ unsigned short Bs[BN][KPAD];
    __shared__ int   r_lds[BM];
    __shared__ float w_lds[BM];

    const int tid = threadIdx.x;
    const int base = e * T_TOK;
    if (tid < BM) {
        const int m = m0 + tid;
        int r = -1; float w = 0.0f;
        if (m < n_e) { r = row_list[base + m]; w = wgt_list[base + m]; }
        r_lds[tid] = r; w_lds[tid] = w;
    }
    __syncthreads();

    const int ar = tid >> 1;
    const int ac = (tid & 1) * 16;
    const int arow = r_lds[ar];
    const unsigned short* ap = act + (size_t)(arow < 0 ? 0 : arow) * IDIM + ks;
    const int brow = tid >> 2;
    const int bch  = (tid & 3) * 8;
    const unsigned short* bsrc = dwp + (size_t)(n0 + brow) * IDIM + ks + bch;
    unsigned short* Bdst = &Bs[0][0] + brow * KPAD + bch;

    const int wv = tid >> 6, lane = tid & 63;
    const int wm = (wv & 1) * 64, wn = (wv >> 1) * 32;
    const int l16 = lane & 15, quad = lane >> 4;

    f32x4 acc[4][2];
    const f32x4 zero = {0.0f, 0.0f, 0.0f, 0.0f};
#pragma unroll
    for (int i = 0; i < 4; ++i)
#pragma unroll
        for (int j = 0; j < 2; ++j) acc[i][j] = zero;

    uint4 PA0 = {0,0,0,0}, PA1 = {0,0,0,0}, PB;
    if (arow >= 0) {
        PA0 = *(const uint4*)(ap + ac);
        PA1 = *(const uint4*)(ap + ac + 8);
    }
    PB = *(const uint4*)(bsrc);

    for (int k0 = 0; k0 < DK_HALF; k0 += BK) {
        __syncthreads();
        *(uint4*)&As[ar][ac]     = PA0;
        *(uint4*)&As[ar][ac + 8] = PA1;
        *(uint4*)(Bdst)          = PB;
        __syncthreads();

        const int kn = k0 + BK;
        if (kn < DK_HALF) {
            if (arow >= 0) {
                PA0 = *(const uint4*)(ap + kn + ac);
                PA1 = *(const uint4*)(ap + kn + ac + 8);
            }
            PB = *(const uint4*)(bsrc + kn);
        }

        bf16x8 af[4], bfr[2];
#pragma unroll
        for (int i = 0; i < 4; ++i)
            af[i] = *(const bf16x8*)&As[wm + i * 16 + l16][quad * 8];
#pragma unroll
        for (int j = 0; j < 2; ++j)
            bfr[j] = *(const bf16x8*)&Bs[wn + j * 16 + l16][quad * 8];
#pragma unroll
        for (int i = 0; i < 4; ++i)
#pragma unroll
            for (int j = 0; j < 2; ++j)
                acc[i][j] = __builtin_amdgcn_mfma_f32_16x16x32_bf16(
                    af[i], bfr[j], acc[i][j], 0, 0, 0);
    }

#pragma unroll
    for (int j = 0; j < 2; ++j) {
        const int nl = n0 + wn + j * 16 + l16;
        const float bv = (sk == 0) ? dbp[nl] : 0.0f;
#pragma unroll
        for (int i = 0; i < 4; ++i) {
#pragma unroll
            for (int ii = 0; ii < 4; ++ii) {
                const int ml = wm + i * 16 + quad * 4 + ii;
                const int rr = r_lds[ml];
                if (rr >= 0)
                    y2s[(size_t)rr * HDIM + nl] = w_lds[ml] * (acc[i][j][ii] + bv);
            }
        }
    }
}

// --------------------------------------------------------------- combine ----
__global__ __launch_bounds__(256) void combine_kernel(
    const float* __restrict__ y2, float* __restrict__ out)
{
    const int idx = (blockIdx.x * 256 + threadIdx.x) * 4;   // < T*H
    const int t = idx >> 10;           // HDIM == 1024
    const int h = idx & 1023;
    const float* y2b = y2 + (size_t)2 * T_TOK * HDIM;
    const float4 a0 = *(const float4*)(y2  + ((size_t)2 * t) * HDIM + h);
    const float4 a1 = *(const float4*)(y2  + ((size_t)2 * t + 1) * HDIM + h);
    const float4 b0 = *(const float4*)(y2b + ((size_t)2 * t) * HDIM + h);
    const float4 b1 = *(const float4*)(y2b + ((size_t)2 * t + 1) * HDIM + h);
    float4 o;
    o.x = a0.x + a1.x + b0.x + b1.x;
    o.y = a0.y + a1.y + b0.y + b1.y;
    o.z = a0.z + a1.z + b0.z + b1.z;
    o.w = a0.w + a1.w + b0.w + b1.w;
    *(float4*)(out + idx) = o;
}

// ---------------------------------------------------------------- launch ----
extern "C" void kernel_launch(void* const* d_in, const int* in_sizes, int n_in,
                              void* d_out, int out_size, void* d_ws, size_t ws_size,
                              hipStream_t stream)
{
    const float* x      = (const float*)d_in[0];
    const float* rw     = (const float*)d_in[1];
    const float* gate_w = (const float*)d_in[2];
    const float* up_w   = (const float*)d_in[3];
    const float* down_w = (const float*)d_in[4];
    const float* gate_b = (const float*)d_in[5];
    const float* up_b   = (const float*)d_in[6];
    const float* down_b = (const float*)d_in[7];
    float* out = (float*)d_out;

    // workspace layout (~85 MB; y2[2 slices, 32 MB] aliases gwt+uwt,
    // which are dead after gateup)
    char* ws = (char*)d_ws;
    size_t off = 0;
    int*   counts   = (int*)(ws + off);  off += 256;
    int*   tok_list = (int*)(ws + off);  off += 65536;
    float* wgt_list = (float*)(ws + off); off += 65536;
    int*   row_list = (int*)(ws + off);  off += 65536;
    unsigned short* x_bf = (unsigned short*)(ws + off); off += (size_t)T_TOK * HDIM * 2;       // 4 MB
    unsigned short* act  = (unsigned short*)(ws + off); off += (size_t)2 * T_TOK * IDIM * 2;   // 11.5 MB
    unsigned short* dwt  = (unsigned short*)(ws + off); off += (size_t)NEXP * IDIM * HDIM * 2; // 23 MB
    unsigned short* gwt  = (unsigned short*)(ws + off); off += (size_t)NEXP * IDIM * HDIM * 2; // 23 MB
    unsigned short* uwt  = (unsigned short*)(ws + off);                                        // 23 MB
    float* y2 = (float*)gwt;   // 2 x 16 MB slices, reused after gateup

    (void)hipMemsetAsync(counts, 0, 256, stream);

    wtrans_all_kernel<<<dim3(176, 1, 24), 256, 0, stream>>>(
        gate_w, up_w, down_w, gwt, uwt, dwt);

    router_kernel<<<T_TOK / 4, 256, 0, stream>>>(x, rw, counts, tok_list,
                                                 wgt_list, row_list, x_bf);

    gateup_kernel<<<8 * GU_NT * MT_SLOTS, 256, 0, stream>>>(
        x_bf, gwt, uwt, gate_b, up_b, counts, tok_list, row_list, act);

    down_kernel<<<2 * 8 * DN_NT * MT_SLOTS, 256, 0, stream>>>(
        act, dwt, down_b, counts, wgt_list, row_list, y2);

    combine_kernel<<<(T_TOK * HDIM / 4) / 256, 256, 0, stream>>>(y2, out);
}

// Round 11
// 288.806 us; speedup vs baseline: 1.5533x; 1.1320x over previous
//
#include <hip/hip_runtime.h>

// DeepseekV3MoEToA2AAdapter: T=2048 tokens, H=1024, E=8, I=1408, top-2.
// fp32 I/O. Register-transpose weight cast -> bf16 [E][N][K]; atomic-free
// router (compute pass + single-block LDS scatter); r8-style MFMA GEMMs;
// non-atomic split-K down + 4-way combine.
#define T_TOK 2048
#define HDIM  1024
#define NEXP  8
#define IDIM  1408

#define BM 128
#define BN 64
#define BK 32
#define KPAD 40     // bf16 elems; 80 B rows, 16B-aligned
#define MT_SLOTS 16
#define GU_NT 22    // IDIM / BN
#define DN_NT 16    // HDIM / BN
#define DK_HALF 704 // IDIM / 2 (split-K for down)

typedef __attribute__((ext_vector_type(8))) short bf16x8;
typedef __attribute__((ext_vector_type(4))) float f32x4;

static __device__ __forceinline__ unsigned short f2bf(float f) {
    union { float f; unsigned u; } a; a.f = f;
    return (unsigned short)((a.u + 0x7fffu + ((a.u >> 16) & 1u)) >> 16);
}

// ------------------------------------------- router pass 1: compute ---------
// One wave per token; fp64 ladder (robust top-2 ordering); fused x->bf16.
// NO device-scope atomics: writes sel[t] = e1 | (e2<<8) and w1[t].
__global__ __launch_bounds__(256) void router_compute_kernel(
    const float* __restrict__ x,        // [T, H]
    const float* __restrict__ rw,       // [H, E]
    int*   __restrict__ sel,            // [T]
    float* __restrict__ w1arr,          // [T]
    unsigned short* __restrict__ xb)    // [T, H] bf16
{
    __shared__ float rwT[NEXP][HDIM];   // 32 KB
    const int tid = threadIdx.x;
#pragma unroll
    for (int p = 0; p < 4; ++p) {
        const int h = tid + 256 * p;
        const float4 a = *(const float4*)(rw + (size_t)h * 8);
        const float4 b = *(const float4*)(rw + (size_t)h * 8 + 4);
        rwT[0][h] = a.x; rwT[1][h] = a.y; rwT[2][h] = a.z; rwT[3][h] = a.w;
        rwT[4][h] = b.x; rwT[5][h] = b.y; rwT[6][h] = b.z; rwT[7][h] = b.w;
    }
    __syncthreads();

    const int wave = (blockIdx.x * blockDim.x + threadIdx.x) >> 6;
    const int lane = threadIdx.x & 63;
    if (wave >= T_TOK) return;
    const int t = wave;

    float xr[16];
    const float* xp = x + (size_t)t * HDIM;
#pragma unroll
    for (int i = 0; i < 16; ++i) xr[i] = xp[lane + 64 * i];

    unsigned short* xbp = xb + (size_t)t * HDIM;
#pragma unroll
    for (int i = 0; i < 16; ++i) xbp[lane + 64 * i] = f2bf(xr[i]);

    double logits[NEXP];
#pragma unroll
    for (int e = 0; e < NEXP; ++e) {
        double s = 0.0;
#pragma unroll
        for (int i = 0; i < 16; ++i)
            s += (double)xr[i] * (double)rwT[e][lane + 64 * i];
#pragma unroll
        for (int off = 32; off > 0; off >>= 1)
            s += __shfl_down(s, off, 64);
        logits[e] = s;
    }

    if (lane == 0) {
        int e1 = 0;
        for (int e = 1; e < NEXP; ++e) if (logits[e] > logits[e1]) e1 = e;
        int e2 = -1;
        for (int e = 0; e < NEXP; ++e) {
            if (e == e1) continue;
            if (e2 < 0 || logits[e] > logits[e2]) e2 = e;
        }
        const double w1 = 1.0 / (1.0 + exp(logits[e2] - logits[e1]));
        sel[t]   = e1 | (e2 << 8);
        w1arr[t] = (float)w1;
    }
}

// ------------------------------------------- router pass 2: scatter ---------
// ONE block, 1024 threads. All fetch-adds are LDS-scope (single CU) -> no
// cross-XCD fabric serialization. List order within an expert is irrelevant.
__global__ __launch_bounds__(1024) void router_scatter_kernel(
    const int* __restrict__ sel, const float* __restrict__ w1arr,
    int* __restrict__ counts,
    int* __restrict__ tok_list, float* __restrict__ wgt_list,
    int* __restrict__ row_list)
{
    __shared__ int cnt[NEXP];
    const int tid = threadIdx.x;
    if (tid < NEXP) cnt[tid] = 0;
    __syncthreads();
    for (int t = tid; t < T_TOK; t += 1024) {
        const int s  = sel[t];
        const int e1 = s & 255, e2 = s >> 8;
        const float w1 = w1arr[t];
        const int p1 = atomicAdd(&cnt[e1], 1);
        tok_list[e1 * T_TOK + p1] = t;
        wgt_list[e1 * T_TOK + p1] = w1;
        row_list[e1 * T_TOK + p1] = 2 * t;
        const int p2 = atomicAdd(&cnt[e2], 1);
        tok_list[e2 * T_TOK + p2] = t;
        wgt_list[e2 * T_TOK + p2] = 1.0f - w1;
        row_list[e2 * T_TOK + p2] = 2 * t + 1;
    }
    __syncthreads();
    if (tid < NEXP) counts[tid] = cnt[tid];
}

// ---------------------- weight cast+transpose, register-only (no LDS) -------
// fp32 [E][K][N] -> bf16 [E][N][K]. Lane owns an 8k x 4n micro-tile.
__global__ __launch_bounds__(256) void wtrans_all_kernel(
    const float* __restrict__ gw, const float* __restrict__ uw,
    const float* __restrict__ dw,
    unsigned short* __restrict__ gwt, unsigned short* __restrict__ uwt,
    unsigned short* __restrict__ dwt)
{
    const int z  = blockIdx.z;
    const int bx = blockIdx.x;          // 0..175
    const float* src; unsigned short* dst; int K, N, kb, nb;
    if (z < 16) {
        K = HDIM; N = IDIM;
        const int e = z & 7;
        src = (z < 8 ? gw : uw) + (size_t)e * K * N;
        dst = (z < 8 ? gwt : uwt) + (size_t)e * (size_t)N * K;
        nb = bx % 11; kb = bx / 11;     // 11 n-tiles x 16 k-tiles
    } else {
        K = IDIM; N = HDIM;
        const int e = z - 16;
        src = dw + (size_t)e * K * N;
        dst = dwt + (size_t)e * (size_t)N * K;
        nb = bx & 7; kb = bx >> 3;      // 8 n-tiles x 22 k-tiles
    }

    const int tid  = threadIdx.x;
    const int wv   = tid >> 6;
    const int lane = tid & 63;
    const int k0 = kb * 64 + (wv >> 1) * 32 + (lane >> 4) * 8;   // 8 k rows
    const int n0 = nb * 128 + (wv & 1) * 64 + (lane & 15) * 4;   // 4 n cols

    float4 v[8];
#pragma unroll
    for (int r = 0; r < 8; ++r)
        v[r] = *(const float4*)(src + (size_t)(k0 + r) * N + n0);

#pragma unroll
    for (int i = 0; i < 4; ++i) {
        ushort4 lo, hi;
        lo.x = f2bf(((const float*)&v[0])[i]);
        lo.y = f2bf(((const float*)&v[1])[i]);
        lo.z = f2bf(((const float*)&v[2])[i]);
        lo.w = f2bf(((const float*)&v[3])[i]);
        hi.x = f2bf(((const float*)&v[4])[i]);
        hi.y = f2bf(((const float*)&v[5])[i]);
        hi.z = f2bf(((const float*)&v[6])[i]);
        hi.w = f2bf(((const float*)&v[7])[i]);
        unsigned short* dp = dst + (size_t)(n0 + i) * K + k0;
        *(ushort4*)(dp)     = lo;
        *(ushort4*)(dp + 4) = hi;
    }
}

// -------------------------------------------------- fused gate+up GEMM -----
__global__ __launch_bounds__(256) void gateup_kernel(
    const unsigned short* __restrict__ xb,    // [T,H] bf16
    const unsigned short* __restrict__ gwt,   // [E][I][H] bf16
    const unsigned short* __restrict__ uwt,   // [E][I][H] bf16
    const float* __restrict__ gb, const float* __restrict__ ub,
    const int* __restrict__ counts,
    const int* __restrict__ tok_list,
    const int* __restrict__ row_list,
    unsigned short* __restrict__ act)         // [2T, IDIM] bf16
{
    const int flat = blockIdx.x;
    const int xcd  = flat & 7;
    const int q    = flat >> 3;
    const int mt   = q & 15;
    const int slot = q >> 4;
    const int P    = slot * 8 + xcd;   // 0..175 = (e, nt), fixed XCD per (e,nt)
    const int e    = P / GU_NT;
    const int nt   = P % GU_NT;
    const int n_e  = counts[e];
    const int m0   = mt * BM;
    if (m0 >= n_e) return;
    const int n0 = nt * BN;

    const unsigned short* gwp = gwt + (size_t)e * IDIM * HDIM;
    const unsigned short* uwp = uwt + (size_t)e * IDIM * HDIM;
    const float* gbp = gb + (size_t)e * IDIM;
    const float* ubp = ub + (size_t)e * IDIM;

    __shared__ unsigned short As[BM][KPAD];
    __shared__ unsigned short Bg[BN][KPAD];
    __shared__ unsigned short Bu[BN][KPAD];
    __shared__ int gr_lds[BM];
    __shared__ int or_lds[BM];

    const int tid = threadIdx.x;
    const int base = e * T_TOK;
    if (tid < BM) {
        const int m = m0 + tid;
        int g = -1, o = -1;
        if (m < n_e) { g = tok_list[base + m]; o = row_list[base + m]; }
        gr_lds[tid] = g; or_lds[tid] = o;
    }
    __syncthreads();

    const int ar = tid >> 1;
    const int ac = (tid & 1) * 16;
    const int arow = gr_lds[ar];
    const unsigned short* ap = xb + (size_t)(arow < 0 ? 0 : arow) * HDIM;
    const int u   = tid & 127;
    const int brow = u >> 1;
    const int bch  = (u & 1) * 16;
    const unsigned short* bsrc =
        ((tid >> 7) ? uwp : gwp) + (size_t)(n0 + brow) * HDIM + bch;
    unsigned short* Bdst =
        ((tid >> 7) ? &Bu[0][0] : &Bg[0][0]) + brow * KPAD + bch;

    const int wv = tid >> 6, lane = tid & 63;
    const int wm = (wv & 1) * 64, wn = (wv >> 1) * 32;
    const int l16 = lane & 15, quad = lane >> 4;

    f32x4 accg[4][2], accu[4][2];
    const f32x4 zero = {0.0f, 0.0f, 0.0f, 0.0f};
#pragma unroll
    for (int i = 0; i < 4; ++i)
#pragma unroll
        for (int j = 0; j < 2; ++j) { accg[i][j] = zero; accu[i][j] = zero; }

    uint4 PA0 = {0,0,0,0}, PA1 = {0,0,0,0}, PB0, PB1;
    if (arow >= 0) {
        PA0 = *(const uint4*)(ap + ac);
        PA1 = *(const uint4*)(ap + ac + 8);
    }
    PB0 = *(const uint4*)(bsrc);
    PB1 = *(const uint4*)(bsrc + 8);

    for (int k0 = 0; k0 < HDIM; k0 += BK) {
        __syncthreads();
        *(uint4*)&As[ar][ac]       = PA0;
        *(uint4*)&As[ar][ac + 8]   = PA1;
        *(uint4*)(Bdst)            = PB0;
        *(uint4*)(Bdst + 8)        = PB1;
        __syncthreads();

        const int kn = k0 + BK;
        if (kn < HDIM) {
            if (arow >= 0) {
                PA0 = *(const uint4*)(ap + kn + ac);
                PA1 = *(const uint4*)(ap + kn + ac + 8);
            }
            PB0 = *(const uint4*)(bsrc + kn);
            PB1 = *(const uint4*)(bsrc + kn + 8);
        }

        bf16x8 af[4], bgf[2], buf[2];
#pragma unroll
        for (int i = 0; i < 4; ++i)
            af[i] = *(const bf16x8*)&As[wm + i * 16 + l16][quad * 8];
#pragma unroll
        for (int j = 0; j < 2; ++j) {
            bgf[j] = *(const bf16x8*)&Bg[wn + j * 16 + l16][quad * 8];
            buf[j] = *(const bf16x8*)&Bu[wn + j * 16 + l16][quad * 8];
        }
#pragma unroll
        for (int i = 0; i < 4; ++i)
#pragma unroll
            for (int j = 0; j < 2; ++j) {
                accg[i][j] = __builtin_amdgcn_mfma_f32_16x16x32_bf16(
                    af[i], bgf[j], accg[i][j], 0, 0, 0);
                accu[i][j] = __builtin_amdgcn_mfma_f32_16x16x32_bf16(
                    af[i], buf[j], accu[i][j], 0, 0, 0);
            }
    }

    // epilogue: silu(g)*u -> bf16 act
#pragma unroll
    for (int j = 0; j < 2; ++j) {
        const int nl = n0 + wn + j * 16 + l16;
        const float gbv = gbp[nl];
        const float ubv = ubp[nl];
#pragma unroll
        for (int i = 0; i < 4; ++i) {
#pragma unroll
            for (int ii = 0; ii < 4; ++ii) {
                const int ml = wm + i * 16 + quad * 4 + ii;
                const int orow = or_lds[ml];
                if (orow >= 0) {
                    const float g = accg[i][j][ii] + gbv;
                    const float uu = accu[i][j][ii] + ubv;
                    act[(size_t)orow * IDIM + nl] =
                        f2bf(g * uu / (1.0f + __expf(-g)));
                }
            }
        }
    }
}

// ------------------------------------------------------- down-proj GEMM ----
// Split-K=2, NON-ATOMIC: slice sk writes plain stores into y2 + sk*(2T*H).
__global__ __launch_bounds__(256) void down_kernel(
    const unsigned short* __restrict__ act,   // [2T, IDIM] bf16
    const unsigned short* __restrict__ dwt,   // [E][H][I] bf16
    const float* __restrict__ db,
    const int* __restrict__ counts,
    const float* __restrict__ wgt_list,
    const int* __restrict__ row_list,
    float* __restrict__ y2)                   // [2][2T, HDIM] fp32
{
    const int flat = blockIdx.x;
    const int xcd  = flat & 7;
    const int q    = flat >> 3;
    const int mt   = q & 15;
    const int slot = q >> 4;
    const int P    = slot * 8 + xcd;   // 0..255 = (sk, e, nt)
    const int sk   = P & 1;
    const int en   = P >> 1;
    const int e    = en >> 4;
    const int nt   = en & 15;
    const int n_e  = counts[e];
    const int m0   = mt * BM;
    if (m0 >= n_e) return;
    const int n0 = nt * BN;
    const int ks = sk * DK_HALF;
    float* y2s = y2 + (size_t)sk * 2 * T_TOK * HDIM;

    const unsigned short* dwp = dwt + (size_t)e * HDIM * IDIM;
    const float* dbp = db + (size_t)e * HDIM;

    __shared__ unsigned short As[BM][KPAD];
    __shared__ unsigned short Bs[BN][KPAD];
    __shared__ int   r_lds[BM];
    __shared__ float w_lds[BM];

    const int tid = threadIdx.x;
    const int base = e * T_TOK;
    if (tid < BM) {
        const int m = m0 + tid;
        int r = -1; float w = 0.0f;
        if (m < n_e) { r = row_list[base + m]; w = wgt_list[base + m]; }
        r_lds[tid] = r; w_lds[tid] = w;
    }
    __syncthreads();

    const int ar = tid >> 1;
    const int ac = (tid & 1) * 16;
    const int arow = r_lds[ar];
    const unsigned short* ap = act + (size_t)(arow < 0 ? 0 : arow) * IDIM + ks;
    const int brow = tid >> 2;
    const int bch  = (tid & 3) * 8;
    const unsigned short* bsrc = dwp + (size_t)(n0 + brow) * IDIM + ks + bch;
    unsigned short* Bdst = &Bs[0][0] + brow * KPAD + bch;

    const int wv = tid >> 6, lane = tid & 63;
    const int wm = (wv & 1) * 64, wn = (wv >> 1) * 32;
    const int l16 = lane & 15, quad = lane >> 4;

    f32x4 acc[4][2];
    const f32x4 zero = {0.0f, 0.0f, 0.0f, 0.0f};
#pragma unroll
    for (int i = 0; i < 4; ++i)
#pragma unroll
        for (int j = 0; j < 2; ++j) acc[i][j] = zero;

    uint4 PA0 = {0,0,0,0}, PA1 = {0,0,0,0}, PB;
    if (arow >= 0) {
        PA0 = *(const uint4*)(ap + ac);
        PA1 = *(const uint4*)(ap + ac + 8);
    }
    PB = *(const uint4*)(bsrc);

    for (int k0 = 0; k0 < DK_HALF; k0 += BK) {
        __syncthreads();
        *(uint4*)&As[ar][ac]     = PA0;
        *(uint4*)&As[ar][ac + 8] = PA1;
        *(uint4*)(Bdst)          = PB;
        __syncthreads();

        const int kn = k0 + BK;
        if (kn < DK_HALF) {
            if (arow >= 0) {
                PA0 = *(const uint4*)(ap + kn + ac);
                PA1 = *(const uint4*)(ap + kn + ac + 8);
            }
            PB = *(const uint4*)(bsrc + kn);
        }

        bf16x8 af[4], bfr[2];
#pragma unroll
        for (int i = 0; i < 4; ++i)
            af[i] = *(const bf16x8*)&As[wm + i * 16 + l16][quad * 8];
#pragma unroll
        for (int j = 0; j < 2; ++j)
            bfr[j] = *(const bf16x8*)&Bs[wn + j * 16 + l16][quad * 8];
#pragma unroll
        for (int i = 0; i < 4; ++i)
#pragma unroll
            for (int j = 0; j < 2; ++j)
                acc[i][j] = __builtin_amdgcn_mfma_f32_16x16x32_bf16(
                    af[i], bfr[j], acc[i][j], 0, 0, 0);
    }

#pragma unroll
    for (int j = 0; j < 2; ++j) {
        const int nl = n0 + wn + j * 16 + l16;
        const float bv = (sk == 0) ? dbp[nl] : 0.0f;
#pragma unroll
        for (int i = 0; i < 4; ++i) {
#pragma unroll
            for (int ii = 0; ii < 4; ++ii) {
                const int ml = wm + i * 16 + quad * 4 + ii;
                const int rr = r_lds[ml];
                if (rr >= 0)
                    y2s[(size_t)rr * HDIM + nl] = w_lds[ml] * (acc[i][j][ii] + bv);
            }
        }
    }
}

// --------------------------------------------------------------- combine ----
__global__ __launch_bounds__(256) void combine_kernel(
    const float* __restrict__ y2, float* __restrict__ out)
{
    const int idx = (blockIdx.x * 256 + threadIdx.x) * 4;   // < T*H
    const int t = idx >> 10;           // HDIM == 1024
    const int h = idx & 1023;
    const float* y2b = y2 + (size_t)2 * T_TOK * HDIM;
    const float4 a0 = *(const float4*)(y2  + ((size_t)2 * t) * HDIM + h);
    const float4 a1 = *(const float4*)(y2  + ((size_t)2 * t + 1) * HDIM + h);
    const float4 b0 = *(const float4*)(y2b + ((size_t)2 * t) * HDIM + h);
    const float4 b1 = *(const float4*)(y2b + ((size_t)2 * t + 1) * HDIM + h);
    float4 o;
    o.x = a0.x + a1.x + b0.x + b1.x;
    o.y = a0.y + a1.y + b0.y + b1.y;
    o.z = a0.z + a1.z + b0.z + b1.z;
    o.w = a0.w + a1.w + b0.w + b1.w;
    *(float4*)(out + idx) = o;
}

// ---------------------------------------------------------------- launch ----
extern "C" void kernel_launch(void* const* d_in, const int* in_sizes, int n_in,
                              void* d_out, int out_size, void* d_ws, size_t ws_size,
                              hipStream_t stream)
{
    const float* x      = (const float*)d_in[0];
    const float* rw     = (const float*)d_in[1];
    const float* gate_w = (const float*)d_in[2];
    const float* up_w   = (const float*)d_in[3];
    const float* down_w = (const float*)d_in[4];
    const float* gate_b = (const float*)d_in[5];
    const float* up_b   = (const float*)d_in[6];
    const float* down_b = (const float*)d_in[7];
    float* out = (float*)d_out;

    // workspace layout (~85 MB; y2[2 slices, 32 MB] aliases gwt+uwt,
    // which are dead after gateup)
    char* ws = (char*)d_ws;
    size_t off = 0;
    int*   counts   = (int*)(ws + off);  off += 256;
    int*   tok_list = (int*)(ws + off);  off += 65536;
    float* wgt_list = (float*)(ws + off); off += 65536;
    int*   row_list = (int*)(ws + off);  off += 65536;
    int*   sel      = (int*)(ws + off);  off += T_TOK * 4;
    float* w1arr    = (float*)(ws + off); off += T_TOK * 4;
    unsigned short* x_bf = (unsigned short*)(ws + off); off += (size_t)T_TOK * HDIM * 2;       // 4 MB
    unsigned short* act  = (unsigned short*)(ws + off); off += (size_t)2 * T_TOK * IDIM * 2;   // 11.5 MB
    unsigned short* dwt  = (unsigned short*)(ws + off); off += (size_t)NEXP * IDIM * HDIM * 2; // 23 MB
    unsigned short* gwt  = (unsigned short*)(ws + off); off += (size_t)NEXP * IDIM * HDIM * 2; // 23 MB
    unsigned short* uwt  = (unsigned short*)(ws + off);                                        // 23 MB
    float* y2 = (float*)gwt;   // 2 x 16 MB slices, reused after gateup

    wtrans_all_kernel<<<dim3(176, 1, 24), 256, 0, stream>>>(
        gate_w, up_w, down_w, gwt, uwt, dwt);

    router_compute_kernel<<<T_TOK / 4, 256, 0, stream>>>(x, rw, sel, w1arr, x_bf);

    router_scatter_kernel<<<1, 1024, 0, stream>>>(
        sel, w1arr, counts, tok_list, wgt_list, row_list);

    gateup_kernel<<<8 * GU_NT * MT_SLOTS, 256, 0, stream>>>(
        x_bf, gwt, uwt, gate_b, up_b, counts, tok_list, row_list, act);

    down_kernel<<<2 * 8 * DN_NT * MT_SLOTS, 256, 0, stream>>>(
        act, dwt, down_b, counts, wgt_list, row_list, y2);

    combine_kernel<<<(T_TOK * HDIM / 4) / 256, 256, 0, stream>>>(y2, out);
}